// Round 2
// baseline (301.265 us; speedup 1.0000x reference)
//
#include <hip/hip_runtime.h>
#include <hip/hip_bf16.h>
#include <cmath>

// Problem constants
// B=128, T=256, D=1024, V=32000, E=300
// d_out layout (floats): logits[0..4096000), h_new[4096000), c_new[4227072),
//                        attn[4358144), context[4390912), total 4521984

#define Bc 128
#define Tc 256
#define Dc 1024
#define Vc 32000
#define Ec 300
#define KX 2348   // D + E + D (x = [context, emb, h])
#define N4 4096   // 4*D

// ---------------- Kernel 1: scores[b,t] = enc[b,t,:] . h[b,:] ----------------
__global__ void k_scores(const float* __restrict__ enc, const float* __restrict__ h,
                         float* __restrict__ scores) {
    int w = (blockIdx.x * blockDim.x + threadIdx.x) >> 6;  // global wave id, 0..32767
    int lane = threadIdx.x & 63;
    int b = w >> 8;
    int t = w & 255;
    const float4* e4 = (const float4*)(enc + ((size_t)(b * Tc + t) << 10));
    const float4* h4 = (const float4*)(h + ((size_t)b << 10));
    float d = 0.f;
    #pragma unroll
    for (int j = 0; j < 4; ++j) {
        float4 ev = e4[lane + (j << 6)];
        float4 hv = h4[lane + (j << 6)];
        d += ev.x * hv.x + ev.y * hv.y + ev.z * hv.z + ev.w * hv.w;
    }
    #pragma unroll
    for (int off = 32; off; off >>= 1) d += __shfl_xor(d, off, 64);
    if (lane == 0) scores[w] = d;
}

// ------- Kernel 2: context[b,d] = sum_t enc[b,t,d]*scores[b,t]; softmax -------
__global__ void k_context(const float* __restrict__ enc, const float* __restrict__ scores,
                          float* __restrict__ ctx_out, float* __restrict__ attn_out,
                          float* __restrict__ x_buf) {
    int b = blockIdx.y;       // 0..127
    int dc = blockIdx.x;      // 0..3
    int tid = threadIdx.x;    // 0..255
    __shared__ float s_sc[256];
    __shared__ float red[256];
    s_sc[tid] = scores[(b << 8) + tid];
    __syncthreads();
    int d = (dc << 8) + tid;
    const float* ep = enc + ((size_t)b << 18) + d;   // b*T*D
    float acc = 0.f;
    #pragma unroll 8
    for (int t = 0; t < Tc; ++t) acc += ep[(size_t)t << 10] * s_sc[t];
    ctx_out[(b << 10) + d] = acc;
    x_buf[b * KX + d] = acc;

    if (dc == 0) {
        // softmax over the 256 scores of row b (raw scores; context used raw too)
        float v = s_sc[tid];
        red[tid] = v;
        __syncthreads();
        for (int s = 128; s; s >>= 1) {
            if (tid < s) red[tid] = fmaxf(red[tid], red[tid + s]);
            __syncthreads();
        }
        float m = red[0];
        __syncthreads();
        float e = __expf(v - m);
        red[tid] = e;
        __syncthreads();
        for (int s = 128; s; s >>= 1) {
            if (tid < s) red[tid] += red[tid + s];
            __syncthreads();
        }
        attn_out[(b << 8) + tid] = e / red[0];
    }
}

// ---------- Kernel 3: pack x[b] = [context (done by k2), emb, h] ----------
__global__ void k_pack(const int* __restrict__ idx, const float* __restrict__ emb_table,
                       const float* __restrict__ h, float* __restrict__ x_buf) {
    int b = blockIdx.x;
    int tid = threadIdx.x;
    int row = idx[b];
    float* xb = x_buf + (size_t)b * KX;
    for (int i = tid; i < Ec; i += 256) xb[Dc + i] = emb_table[(size_t)row * Ec + i];
    for (int i = tid; i < Dc; i += 256) xb[Dc + Ec + i] = h[((size_t)b << 10) + i];
}

// ---- Kernel 4: z partials: z_part[ks] += x[:,krange] @ [W_lstm;U_lstm][krange,:] ----
#define KCH 587   // 2348/4
__global__ void k_zgemm(const float* __restrict__ x, const float* __restrict__ W,
                        const float* __restrict__ U, float* __restrict__ z_part) {
    const int n0 = blockIdx.x << 5;         // 32-wide n tile
    const int ks = blockIdx.y;              // 0..3 K-split
    const int kbeg = ks * KCH, kend = kbeg + KCH;
    const int tid = threadIdx.x;
    const int tm = tid >> 3;                // 0..31
    const int tn = tid & 7;                 // 0..7
    __shared__ float sa[32][132];           // [k][m], padded
    __shared__ float sb[32][36];            // [k][n], padded
    float acc[4][4] = {};
    for (int kt = kbeg; kt < kend; kt += 32) {
        #pragma unroll
        for (int j = 0; j < 16; ++j) {
            int i = (j << 8) + tid;         // 0..4095
            int m = i >> 5, k = i & 31;
            int gk = kt + k;
            sa[k][m] = (gk < kend) ? x[m * KX + gk] : 0.f;
        }
        #pragma unroll
        for (int j = 0; j < 4; ++j) {
            int i = (j << 8) + tid;         // 0..1023
            int k = i >> 5, n = i & 31;
            int gk = kt + k;
            float v = 0.f;
            if (gk < kend)
                v = (gk < 1324) ? W[(size_t)gk * N4 + n0 + n]
                                : U[(size_t)(gk - 1324) * N4 + n0 + n];
            sb[k][n] = v;
        }
        __syncthreads();
        #pragma unroll
        for (int k = 0; k < 32; ++k) {
            float4 a = *(const float4*)&sa[k][tm << 2];
            float4 bb = *(const float4*)&sb[k][tn << 2];
            acc[0][0] += a.x * bb.x; acc[0][1] += a.x * bb.y; acc[0][2] += a.x * bb.z; acc[0][3] += a.x * bb.w;
            acc[1][0] += a.y * bb.x; acc[1][1] += a.y * bb.y; acc[1][2] += a.y * bb.z; acc[1][3] += a.y * bb.w;
            acc[2][0] += a.z * bb.x; acc[2][1] += a.z * bb.y; acc[2][2] += a.z * bb.z; acc[2][3] += a.z * bb.w;
            acc[3][0] += a.w * bb.x; acc[3][1] += a.w * bb.y; acc[3][2] += a.w * bb.z; acc[3][3] += a.w * bb.w;
        }
        __syncthreads();
    }
    float* zp = z_part + ((size_t)ks << 19);   // ks * 128*4096
    #pragma unroll
    for (int i = 0; i < 4; ++i)
        #pragma unroll
        for (int j = 0; j < 4; ++j)
            zp[(size_t)((tm << 2) + i) * N4 + n0 + (tn << 2) + j] = acc[i][j];
}

// -------- Kernel 5: sum partials + bias -> gates -> c_new, h_new --------
__global__ void k_gates(const float* __restrict__ z_part, const float* __restrict__ b_lstm,
                        const float* __restrict__ c_in, float* __restrict__ h_new,
                        float* __restrict__ c_new) {
    int i = blockIdx.x * 256 + threadIdx.x;    // < 131072
    int b = i >> 10, d = i & 1023;
    size_t base = ((size_t)b << 12) + d;
    float zi = b_lstm[d], zf = b_lstm[d + 1024], zg = b_lstm[d + 2048], zo = b_lstm[d + 3072];
    #pragma unroll
    for (int ks = 0; ks < 4; ++ks) {
        const float* zp = z_part + ((size_t)ks << 19);
        zi += zp[base];
        zf += zp[base + 1024];
        zg += zp[base + 2048];
        zo += zp[base + 3072];
    }
    float si = 1.f / (1.f + __expf(-zi));
    float sf = 1.f / (1.f + __expf(-zf));
    float so = 1.f / (1.f + __expf(-zo));
    float cn = sf * c_in[i] + si * tanhf(zg);
    float hn = so * tanhf(cn);
    c_new[i] = cn;
    h_new[i] = hn;
}

// -------- Kernel 6: logits = h_new @ W_dense + b_dense  (128x32000, K=1024) --------
__global__ void k_logits(const float* __restrict__ h, const float* __restrict__ Wd,
                         const float* __restrict__ bd, float* __restrict__ out) {
    const int n0 = blockIdx.x << 5;          // 1000 blocks
    const int tid = threadIdx.x;
    const int tm = tid >> 3;                 // 0..31
    const int tn = tid & 7;                  // 0..7
    __shared__ float sa[32][132];            // [k][m]
    __shared__ float sb[32][36];             // [k][n]
    float acc[4][4] = {};
    for (int kt = 0; kt < Dc; kt += 32) {
        #pragma unroll
        for (int j = 0; j < 16; ++j) {
            int i = (j << 8) + tid;
            int m = i >> 5, k = i & 31;
            sa[k][m] = h[((size_t)m << 10) + kt + k];
        }
        #pragma unroll
        for (int j = 0; j < 4; ++j) {
            int i = (j << 8) + tid;
            int k = i >> 5, n = i & 31;
            sb[k][n] = Wd[(size_t)(kt + k) * Vc + n0 + n];
        }
        __syncthreads();
        #pragma unroll
        for (int k = 0; k < 32; ++k) {
            float4 a = *(const float4*)&sa[k][tm << 2];
            float4 bb = *(const float4*)&sb[k][tn << 2];
            acc[0][0] += a.x * bb.x; acc[0][1] += a.x * bb.y; acc[0][2] += a.x * bb.z; acc[0][3] += a.x * bb.w;
            acc[1][0] += a.y * bb.x; acc[1][1] += a.y * bb.y; acc[1][2] += a.y * bb.z; acc[1][3] += a.y * bb.w;
            acc[2][0] += a.z * bb.x; acc[2][1] += a.z * bb.y; acc[2][2] += a.z * bb.z; acc[2][3] += a.z * bb.w;
            acc[3][0] += a.w * bb.x; acc[3][1] += a.w * bb.y; acc[3][2] += a.w * bb.z; acc[3][3] += a.w * bb.w;
        }
        __syncthreads();
    }
    #pragma unroll
    for (int j = 0; j < 4; ++j) {
        float bias = bd[n0 + (tn << 2) + j];
        #pragma unroll
        for (int i = 0; i < 4; ++i)
            out[(size_t)((tm << 2) + i) * Vc + n0 + (tn << 2) + j] = acc[i][j] + bias;
    }
}

extern "C" void kernel_launch(void* const* d_in, const int* in_sizes, int n_in,
                              void* d_out, int out_size, void* d_ws, size_t ws_size,
                              hipStream_t stream) {
    const int*   idx = (const int*)d_in[0];
    const float* enc = (const float*)d_in[1];
    const float* h   = (const float*)d_in[2];
    const float* c   = (const float*)d_in[3];
    const float* emb = (const float*)d_in[4];
    const float* Wl  = (const float*)d_in[5];
    const float* Ul  = (const float*)d_in[6];
    const float* bl  = (const float*)d_in[7];
    const float* Wd  = (const float*)d_in[8];
    const float* bd  = (const float*)d_in[9];

    float* out    = (float*)d_out;
    float* logits = out;                 // 4,096,000
    float* h_new  = out + 4096000;       // 131,072
    float* c_new  = out + 4227072;       // 131,072
    float* attn   = out + 4358144;       // 32,768
    float* ctx    = out + 4390912;       // 131,072

    // Scratch inside the logits region (fully overwritten by k_logits last):
    float* z_part = out;                 // 4 * 524,288 = 2,097,152
    float* x_buf  = out + 2097152;       // 128 * 2348 = 300,544
    float* scores = out + 2397696;       // 32,768  (ends 2,430,464 < 4,096,000)

    hipLaunchKernelGGL(k_scores, dim3(8192), dim3(256), 0, stream, enc, h, scores);
    hipLaunchKernelGGL(k_context, dim3(4, 128), dim3(256), 0, stream, enc, scores, ctx, attn, x_buf);
    hipLaunchKernelGGL(k_pack, dim3(128), dim3(256), 0, stream, idx, emb, h, x_buf);
    hipLaunchKernelGGL(k_zgemm, dim3(128, 4), dim3(256), 0, stream, x_buf, Wl, Ul, z_part);
    hipLaunchKernelGGL(k_gates, dim3(512), dim3(256), 0, stream, z_part, bl, c, h_new, c_new);
    hipLaunchKernelGGL(k_logits, dim3(1000), dim3(256), 0, stream, h_new, Wd, bd, logits);
}

// Round 3
// 214.961 us; speedup vs baseline: 1.4015x; 1.4015x over previous
//
#include <hip/hip_runtime.h>
#include <hip/hip_bf16.h>
#include <cmath>

// Problem constants
// B=128, T=256, D=1024, V=32000, E=300
// d_out layout (floats): logits[0..4096000), h_new[4096000), c_new[4227072),
//                        attn[4358144), context[4390912), total 4521984

#define Bc 128
#define Tc 256
#define Dc 1024
#define Vc 32000
#define Ec 300
#define KX 2348   // D + E + D (x = [context, emb, h])
#define N4 4096   // 4*D

typedef __attribute__((ext_vector_type(8))) short bf16x8;
typedef __attribute__((ext_vector_type(4))) float f32x4;

static __device__ __forceinline__ short f2bf(float x) {
    __hip_bfloat16 b = __float2bfloat16(x);   // RNE
    return *reinterpret_cast<short*>(&b);
}

// ---------------- Kernel 1: scores[b,t] = enc[b,t,:] . h[b,:] ----------------
__global__ void k_scores(const float* __restrict__ enc, const float* __restrict__ h,
                         float* __restrict__ scores) {
    int w = (blockIdx.x * blockDim.x + threadIdx.x) >> 6;  // global wave id, 0..32767
    int lane = threadIdx.x & 63;
    int b = w >> 8;
    int t = w & 255;
    const float4* e4 = (const float4*)(enc + ((size_t)(b * Tc + t) << 10));
    const float4* h4 = (const float4*)(h + ((size_t)b << 10));
    float d = 0.f;
    #pragma unroll
    for (int j = 0; j < 4; ++j) {
        float4 ev = e4[lane + (j << 6)];
        float4 hv = h4[lane + (j << 6)];
        d += ev.x * hv.x + ev.y * hv.y + ev.z * hv.z + ev.w * hv.w;
    }
    #pragma unroll
    for (int off = 32; off; off >>= 1) d += __shfl_xor(d, off, 64);
    if (lane == 0) scores[w] = d;
}

// ------- Kernel 2: context[b,d] = sum_t enc[b,t,d]*scores[b,t]; softmax -------
__global__ void k_context(const float* __restrict__ enc, const float* __restrict__ scores,
                          float* __restrict__ ctx_out, float* __restrict__ attn_out,
                          float* __restrict__ x_buf) {
    int b = blockIdx.y;       // 0..127
    int dc = blockIdx.x;      // 0..3
    int tid = threadIdx.x;    // 0..255
    __shared__ float s_sc[256];
    __shared__ float red[256];
    s_sc[tid] = scores[(b << 8) + tid];
    __syncthreads();
    int d = (dc << 8) + tid;
    const float* ep = enc + ((size_t)b << 18) + d;   // b*T*D
    float acc = 0.f;
    #pragma unroll 8
    for (int t = 0; t < Tc; ++t) acc += ep[(size_t)t << 10] * s_sc[t];
    ctx_out[(b << 10) + d] = acc;
    x_buf[b * KX + d] = acc;

    if (dc == 0) {
        float v = s_sc[tid];
        red[tid] = v;
        __syncthreads();
        for (int s = 128; s; s >>= 1) {
            if (tid < s) red[tid] = fmaxf(red[tid], red[tid + s]);
            __syncthreads();
        }
        float m = red[0];
        __syncthreads();
        float e = __expf(v - m);
        red[tid] = e;
        __syncthreads();
        for (int s = 128; s; s >>= 1) {
            if (tid < s) red[tid] += red[tid + s];
            __syncthreads();
        }
        attn_out[(b << 8) + tid] = e / red[0];
    }
}

// ---------- Kernel 3: pack x[b] = [context (done by k2), emb, h] ----------
__global__ void k_pack(const int* __restrict__ idx, const float* __restrict__ emb_table,
                       const float* __restrict__ h, float* __restrict__ x_buf) {
    int b = blockIdx.x;
    int tid = threadIdx.x;
    int row = idx[b];
    float* xb = x_buf + (size_t)b * KX;
    for (int i = tid; i < Ec; i += 256) xb[Dc + i] = emb_table[(size_t)row * Ec + i];
    for (int i = tid; i < Dc; i += 256) xb[Dc + Ec + i] = h[((size_t)b << 10) + i];
}

// ---- Kernel 4: z partials: z_part[ks] += x[:,krange] @ [W_lstm;U_lstm][krange,:] ----
#define KCH 587   // 2348/4
__global__ void k_zgemm(const float* __restrict__ x, const float* __restrict__ W,
                        const float* __restrict__ U, float* __restrict__ z_part) {
    const int n0 = blockIdx.x << 5;         // 32-wide n tile
    const int ks = blockIdx.y;              // 0..3 K-split
    const int kbeg = ks * KCH, kend = kbeg + KCH;
    const int tid = threadIdx.x;
    const int tm = tid >> 3;                // 0..31
    const int tn = tid & 7;                 // 0..7
    __shared__ float sa[32][132];           // [k][m], padded
    __shared__ float sb[32][36];            // [k][n], padded
    float acc[4][4] = {};
    for (int kt = kbeg; kt < kend; kt += 32) {
        #pragma unroll
        for (int j = 0; j < 16; ++j) {
            int i = (j << 8) + tid;         // 0..4095
            int m = i >> 5, k = i & 31;
            int gk = kt + k;
            sa[k][m] = (gk < kend) ? x[m * KX + gk] : 0.f;
        }
        #pragma unroll
        for (int j = 0; j < 4; ++j) {
            int i = (j << 8) + tid;         // 0..1023
            int k = i >> 5, n = i & 31;
            int gk = kt + k;
            float v = 0.f;
            if (gk < kend)
                v = (gk < 1324) ? W[(size_t)gk * N4 + n0 + n]
                                : U[(size_t)(gk - 1324) * N4 + n0 + n];
            sb[k][n] = v;
        }
        __syncthreads();
        #pragma unroll
        for (int k = 0; k < 32; ++k) {
            float4 a = *(const float4*)&sa[k][tm << 2];
            float4 bb = *(const float4*)&sb[k][tn << 2];
            acc[0][0] += a.x * bb.x; acc[0][1] += a.x * bb.y; acc[0][2] += a.x * bb.z; acc[0][3] += a.x * bb.w;
            acc[1][0] += a.y * bb.x; acc[1][1] += a.y * bb.y; acc[1][2] += a.y * bb.z; acc[1][3] += a.y * bb.w;
            acc[2][0] += a.z * bb.x; acc[2][1] += a.z * bb.y; acc[2][2] += a.z * bb.z; acc[2][3] += a.z * bb.w;
            acc[3][0] += a.w * bb.x; acc[3][1] += a.w * bb.y; acc[3][2] += a.w * bb.z; acc[3][3] += a.w * bb.w;
        }
        __syncthreads();
    }
    float* zp = z_part + ((size_t)ks << 19);   // ks * 128*4096
    #pragma unroll
    for (int i = 0; i < 4; ++i)
        #pragma unroll
        for (int j = 0; j < 4; ++j)
            zp[(size_t)((tm << 2) + i) * N4 + n0 + (tn << 2) + j] = acc[i][j];
}

// -------- Kernel 5: sum partials + bias -> gates -> c_new, h_new --------
__global__ void k_gates(const float* __restrict__ z_part, const float* __restrict__ b_lstm,
                        const float* __restrict__ c_in, float* __restrict__ h_new,
                        float* __restrict__ c_new) {
    int i = blockIdx.x * 256 + threadIdx.x;    // < 131072
    int b = i >> 10, d = i & 1023;
    size_t base = ((size_t)b << 12) + d;
    float zi = b_lstm[d], zf = b_lstm[d + 1024], zg = b_lstm[d + 2048], zo = b_lstm[d + 3072];
    #pragma unroll
    for (int ks = 0; ks < 4; ++ks) {
        const float* zp = z_part + ((size_t)ks << 19);
        zi += zp[base];
        zf += zp[base + 1024];
        zg += zp[base + 2048];
        zo += zp[base + 3072];
    }
    float si = 1.f / (1.f + __expf(-zi));
    float sf = 1.f / (1.f + __expf(-zf));
    float so = 1.f / (1.f + __expf(-zo));
    float cn = sf * c_in[i] + si * tanhf(zg);
    float hn = so * tanhf(cn);
    c_new[i] = cn;
    h_new[i] = hn;
}

// -------- Kernel 6: logits = h_new @ W_dense + b_dense via bf16 MFMA --------
// Grid: 250 blocks (N-tile 128), 512 threads = 8 waves (wave = 16-row M-tile).
// Per K-step 64: W staged f32->bf16 into LDS in fragment-major layout
// [ks][ntile][lane][j] so each lane's B-fragment is one contiguous 16B read.
__global__ __launch_bounds__(512) void k_logits_mfma(
        const float* __restrict__ h, const float* __restrict__ Wd,
        const float* __restrict__ bd, float* __restrict__ out) {
    __shared__ short blds[2][8][64][8];     // 16 KB
    const int tid  = threadIdx.x;
    const int wid  = tid >> 6;              // 0..7 -> M-tile row base wid*16
    const int lane = tid & 63;
    const int g    = lane >> 4;             // k-group 0..3
    const int r    = lane & 15;
    const int n0   = blockIdx.x << 7;       // N-tile base

    f32x4 acc[8] = {};
    const float* hrow = h + ((size_t)((wid << 4) + r) << 10);  // A row for this lane

    for (int kt = 0; kt < Dc; kt += 64) {
        // ---- stage W[kt..kt+63][n0..n0+127] as bf16 pairs ----
        #pragma unroll
        for (int t = 0; t < 2; ++t) {
            int task = (t << 9) + tid;      // 0..1023 = pr(32) x c(32)
            int pr = task >> 5;             // pair-row: k = 2pr, 2pr+1
            int c  = task & 31;             // n = 4c..4c+3
            const float* w0 = Wd + (size_t)(kt + (pr << 1)) * Vc + n0 + (c << 2);
            float4 wa = *(const float4*)w0;
            float4 wb = *(const float4*)(w0 + Vc);
            int ks = pr >> 4;
            int kk = (pr << 1) & 31;
            int gg = kk >> 3;
            int jj = kk & 7;                // even
            float a0[4] = {wa.x, wa.y, wa.z, wa.w};
            float b0[4] = {wb.x, wb.y, wb.z, wb.w};
            #pragma unroll
            for (int i = 0; i < 4; ++i) {
                int n = (c << 2) + i;
                unsigned lo = (unsigned short)f2bf(a0[i]);
                unsigned hi = (unsigned short)f2bf(b0[i]);
                unsigned pk = lo | (hi << 16);
                *(unsigned*)&blds[ks][n >> 4][(gg << 4) | (n & 15)][jj] = pk;
            }
        }
        __syncthreads();

        // ---- compute: 2 ks x 8 ntiles ----
        #pragma unroll
        for (int ks = 0; ks < 2; ++ks) {
            const float* hp = hrow + kt + (ks << 5) + (g << 3);
            float4 h0 = *(const float4*)hp;
            float4 h1 = *(const float4*)(hp + 4);
            bf16x8 af;
            af[0] = f2bf(h0.x); af[1] = f2bf(h0.y); af[2] = f2bf(h0.z); af[3] = f2bf(h0.w);
            af[4] = f2bf(h1.x); af[5] = f2bf(h1.y); af[6] = f2bf(h1.z); af[7] = f2bf(h1.w);
            #pragma unroll
            for (int nt = 0; nt < 8; ++nt) {
                bf16x8 bfr = *(const bf16x8*)&blds[ks][nt][lane][0];
                acc[nt] = __builtin_amdgcn_mfma_f32_16x16x32_bf16(af, bfr, acc[nt], 0, 0, 0);
            }
        }
        __syncthreads();
    }

    // ---- epilogue: D row = 4g + j, col = r (within 16x16 tile) ----
    #pragma unroll
    for (int nt = 0; nt < 8; ++nt) {
        int col = n0 + (nt << 4) + r;
        float bias = bd[col];
        #pragma unroll
        for (int j = 0; j < 4; ++j) {
            int row = (wid << 4) + (g << 2) + j;
            out[(size_t)row * Vc + col] = acc[nt][j] + bias;
        }
    }
}

extern "C" void kernel_launch(void* const* d_in, const int* in_sizes, int n_in,
                              void* d_out, int out_size, void* d_ws, size_t ws_size,
                              hipStream_t stream) {
    const int*   idx = (const int*)d_in[0];
    const float* enc = (const float*)d_in[1];
    const float* h   = (const float*)d_in[2];
    const float* c   = (const float*)d_in[3];
    const float* emb = (const float*)d_in[4];
    const float* Wl  = (const float*)d_in[5];
    const float* Ul  = (const float*)d_in[6];
    const float* bl  = (const float*)d_in[7];
    const float* Wd  = (const float*)d_in[8];
    const float* bd  = (const float*)d_in[9];

    float* out    = (float*)d_out;
    float* logits = out;                 // 4,096,000
    float* h_new  = out + 4096000;       // 131,072
    float* c_new  = out + 4227072;       // 131,072
    float* attn   = out + 4358144;       // 32,768
    float* ctx    = out + 4390912;       // 131,072

    // Scratch inside the logits region (fully overwritten by k_logits_mfma last):
    float* z_part = out;                 // 4 * 524,288 = 2,097,152
    float* x_buf  = out + 2097152;       // 128 * 2348 = 300,544
    float* scores = out + 2397696;       // 32,768  (ends 2,430,464 < 4,096,000)

    hipLaunchKernelGGL(k_scores, dim3(8192), dim3(256), 0, stream, enc, h, scores);
    hipLaunchKernelGGL(k_context, dim3(4, 128), dim3(256), 0, stream, enc, scores, ctx, attn, x_buf);
    hipLaunchKernelGGL(k_pack, dim3(128), dim3(256), 0, stream, idx, emb, h, x_buf);
    hipLaunchKernelGGL(k_zgemm, dim3(128, 4), dim3(256), 0, stream, x_buf, Wl, Ul, z_part);
    hipLaunchKernelGGL(k_gates, dim3(512), dim3(256), 0, stream, z_part, bl, c, h_new, c_new);
    hipLaunchKernelGGL(k_logits_mfma, dim3(250), dim3(512), 0, stream, h_new, Wd, bd, logits);
}

// Round 4
// 126.747 us; speedup vs baseline: 2.3769x; 1.6960x over previous
//
#include <hip/hip_runtime.h>
#include <hip/hip_bf16.h>
#include <cmath>

// B=128, T=256, D=1024, V=32000, E=300
// d_out (floats): logits[0..4096000), h_new[4096000), c_new[4227072),
//                 attn[4358144), context[4390912), total 4521984

#define Bc 128
#define Tc 256
#define Dc 1024
#define Vc 32000
#define Ec 300
#define KXP 2368          // padded K for x = [context(1024), emb(300), h(1024)] + 20 zeros
#define KREAL 2348
#define KSPLIT 7
#define N4 4096           // 4*D

typedef __attribute__((ext_vector_type(8))) short bf16x8;
typedef __attribute__((ext_vector_type(4))) float f32x4;

static __device__ __forceinline__ short f2bf(float x) {
    __hip_bfloat16 b = __float2bfloat16(x);   // RNE
    return *reinterpret_cast<short*>(&b);
}
static __device__ __forceinline__ unsigned pack2(float a, float b) {
    return (unsigned)(unsigned short)f2bf(a) | ((unsigned)(unsigned short)f2bf(b) << 16);
}

// ---- Kernel A1: per (tc,b): scores for 64 t's, then partial context over them ----
__global__ void k_att1(const float* __restrict__ enc, const float* __restrict__ h,
                       float* __restrict__ scores_g, float* __restrict__ ctx_part) {
    const int tc = blockIdx.x;            // 0..3
    const int b  = blockIdx.y;            // 0..127
    const int tid = threadIdx.x;          // 0..255
    const int wave = tid >> 6, lane = tid & 63;
    __shared__ float s_lds[64];

    const float4* h4 = (const float4*)(h + ((size_t)b << 10));
    float4 hv0 = h4[lane], hv1 = h4[lane + 64], hv2 = h4[lane + 128], hv3 = h4[lane + 192];

    // phase 1: 16 dots per wave
    for (int i = 0; i < 16; ++i) {
        int tl = (wave << 4) + i;
        int t  = (tc << 6) + tl;
        const float4* e4 = (const float4*)(enc + ((size_t)(b * Tc + t) << 10));
        float4 e0 = e4[lane], e1 = e4[lane + 64], e2 = e4[lane + 128], e3 = e4[lane + 192];
        float d = e0.x*hv0.x + e0.y*hv0.y + e0.z*hv0.z + e0.w*hv0.w
                + e1.x*hv1.x + e1.y*hv1.y + e1.z*hv1.z + e1.w*hv1.w
                + e2.x*hv2.x + e2.y*hv2.y + e2.z*hv2.z + e2.w*hv2.w
                + e3.x*hv3.x + e3.y*hv3.y + e3.z*hv3.z + e3.w*hv3.w;
        #pragma unroll
        for (int off = 32; off; off >>= 1) d += __shfl_xor(d, off, 64);
        if (lane == 0) { s_lds[tl] = d; scores_g[(b << 8) + t] = d; }
    }
    __syncthreads();

    // phase 2: partial context over this 64-t chunk (L2-warm re-read)
    const float* ep = enc + ((size_t)(b * Tc + (tc << 6)) << 10) + (tid << 2);
    float4 acc = {0.f, 0.f, 0.f, 0.f};
    #pragma unroll 8
    for (int tl = 0; tl < 64; ++tl) {
        float4 v = *(const float4*)(ep + ((size_t)tl << 10));
        float s = s_lds[tl];
        acc.x += s * v.x; acc.y += s * v.y; acc.z += s * v.z; acc.w += s * v.w;
    }
    *(float4*)(ctx_part + (((size_t)(tc << 7) + b) << 10) + (tid << 2)) = acc;
}

// ---- Kernel A2: reduce ctx parts; softmax->attn; pack x = [ctx, emb, h, 0pad] ----
__global__ void k_att2(const float* __restrict__ ctx_part, const float* __restrict__ scores_g,
                       const int* __restrict__ idx, const float* __restrict__ emb_table,
                       const float* __restrict__ h,
                       float* __restrict__ ctx_out, float* __restrict__ attn_out,
                       float* __restrict__ x_buf) {
    const int b = blockIdx.x;
    const int tid = threadIdx.x;          // 0..255
    __shared__ float red[256];

    // context reduce (4 floats per thread)
    float4 s0 = *(const float4*)(ctx_part + (((size_t)(0 << 7) + b) << 10) + (tid << 2));
    float4 s1 = *(const float4*)(ctx_part + (((size_t)(1 << 7) + b) << 10) + (tid << 2));
    float4 s2 = *(const float4*)(ctx_part + (((size_t)(2 << 7) + b) << 10) + (tid << 2));
    float4 s3 = *(const float4*)(ctx_part + (((size_t)(3 << 7) + b) << 10) + (tid << 2));
    float4 cv;
    cv.x = s0.x + s1.x + s2.x + s3.x;
    cv.y = s0.y + s1.y + s2.y + s3.y;
    cv.z = s0.z + s1.z + s2.z + s3.z;
    cv.w = s0.w + s1.w + s2.w + s3.w;
    *(float4*)(ctx_out + ((size_t)b << 10) + (tid << 2)) = cv;
    float* xb = x_buf + (size_t)b * KXP;
    *(float4*)(xb + (tid << 2)) = cv;

    // emb + h pack
    int row = idx[b];
    for (int i = tid; i < Ec; i += 256) xb[Dc + i] = emb_table[(size_t)row * Ec + i];
    *(float4*)(xb + Dc + Ec + (tid << 2)) = *(const float4*)(h + ((size_t)b << 10) + (tid << 2));
    if (tid < KXP - KREAL) xb[KREAL + tid] = 0.f;

    // softmax
    float v = scores_g[(b << 8) + tid];
    red[tid] = v;
    __syncthreads();
    for (int s = 128; s; s >>= 1) { if (tid < s) red[tid] = fmaxf(red[tid], red[tid + s]); __syncthreads(); }
    float m = red[0];
    __syncthreads();
    float e = __expf(v - m);
    red[tid] = e;
    __syncthreads();
    for (int s = 128; s; s >>= 1) { if (tid < s) red[tid] += red[tid + s]; __syncthreads(); }
    attn_out[(b << 8) + tid] = e / red[0];
}

// ---- Kernel Z: z partials via bf16 MFMA. Grid (32 n-tiles, 7 k-splits) x 512 ----
__global__ __launch_bounds__(512) void k_zgemm_mfma(
        const float* __restrict__ x, const float* __restrict__ Wl,
        const float* __restrict__ Ul, float* __restrict__ z_part) {
    __shared__ __align__(16) short blds[2 * 8 * 64 * 8];   // 16 KB
    const int tid  = threadIdx.x;
    const int wid  = tid >> 6;            // 0..7
    const int lane = tid & 63;
    const int g    = lane >> 4;
    const int r    = lane & 15;
    const int n0   = blockIdx.x << 7;     // N-tile base (0..4095 step 128)
    const int ksp  = blockIdx.y;          // 0..6
    const int s0   = ksp * 5 + (ksp < 2 ? ksp : 2);
    const int s1   = s0 + 5 + (ksp < 2 ? 1 : 0);

    f32x4 acc[8] = {};
    const float* xrow = x + (size_t)((wid << 4) + r) * KXP;

    for (int s = s0; s < s1; ++s) {
        const int kt = s << 6;
        // stage combined [W;U;0] rows kt..kt+63, cols n0..n0+127 (bf16 pairs)
        #pragma unroll
        for (int t = 0; t < 2; ++t) {
            int task = (t << 9) + tid;    // 0..1023
            int pr = task >> 5;           // 0..31
            int c  = task & 31;
            int gk0 = kt + (pr << 1);
            float4 wa, wb;
            {
                int gk = gk0;
                wa = (gk < 1324) ? *(const float4*)(Wl + (size_t)gk * N4 + n0 + (c << 2))
                   : (gk < KREAL) ? *(const float4*)(Ul + (size_t)(gk - 1324) * N4 + n0 + (c << 2))
                   : float4{0.f, 0.f, 0.f, 0.f};
            }
            {
                int gk = gk0 + 1;
                wb = (gk < 1324) ? *(const float4*)(Wl + (size_t)gk * N4 + n0 + (c << 2))
                   : (gk < KREAL) ? *(const float4*)(Ul + (size_t)(gk - 1324) * N4 + n0 + (c << 2))
                   : float4{0.f, 0.f, 0.f, 0.f};
            }
            int ks = pr >> 4;
            int kk = (pr << 1) & 31;
            int gg = kk >> 3;
            int jj = kk & 7;              // even
            float a0[4] = {wa.x, wa.y, wa.z, wa.w};
            float b0[4] = {wb.x, wb.y, wb.z, wb.w};
            #pragma unroll
            for (int i = 0; i < 4; ++i) {
                int n = (c << 2) + i;
                int nt = n >> 4;
                int inner = (gg << 4) | (n & 15);
                int Xs = ((((ks << 3) + nt) << 6) | inner) ^ nt;   // XOR swizzle
                *(unsigned*)&blds[(Xs << 3) + jj] = pack2(a0[i], b0[i]);
            }
        }
        __syncthreads();

        #pragma unroll
        for (int ks = 0; ks < 2; ++ks) {
            const float* hp = xrow + kt + (ks << 5) + (g << 3);
            float4 h0 = *(const float4*)hp;
            float4 h1 = *(const float4*)(hp + 4);
            bf16x8 af;
            af[0] = f2bf(h0.x); af[1] = f2bf(h0.y); af[2] = f2bf(h0.z); af[3] = f2bf(h0.w);
            af[4] = f2bf(h1.x); af[5] = f2bf(h1.y); af[6] = f2bf(h1.z); af[7] = f2bf(h1.w);
            #pragma unroll
            for (int nt = 0; nt < 8; ++nt) {
                int Xs = ((((ks << 3) + nt) << 6) | lane) ^ nt;
                bf16x8 bfr = *(const bf16x8*)&blds[Xs << 3];
                acc[nt] = __builtin_amdgcn_mfma_f32_16x16x32_bf16(af, bfr, acc[nt], 0, 0, 0);
            }
        }
        __syncthreads();
    }

    float* zp = z_part + ((size_t)ksp << 19);
    #pragma unroll
    for (int nt = 0; nt < 8; ++nt) {
        int col = n0 + (nt << 4) + r;
        #pragma unroll
        for (int j = 0; j < 4; ++j) {
            int rowm = (wid << 4) + (g << 2) + j;
            zp[((size_t)rowm << 12) + col] = acc[nt][j];
        }
    }
}

// ---- Kernel G: sum 7 partials + bias -> gates -> c_new, h_new ----
__global__ void k_gates(const float* __restrict__ z_part, const float* __restrict__ b_lstm,
                        const float* __restrict__ c_in, float* __restrict__ h_new,
                        float* __restrict__ c_new) {
    int i = blockIdx.x * 256 + threadIdx.x;    // < 131072
    int b = i >> 10, d = i & 1023;
    size_t base = ((size_t)b << 12) + d;
    float zi = b_lstm[d], zf = b_lstm[d + 1024], zg = b_lstm[d + 2048], zo = b_lstm[d + 3072];
    #pragma unroll
    for (int ks = 0; ks < KSPLIT; ++ks) {
        const float* zp = z_part + ((size_t)ks << 19);
        zi += zp[base];
        zf += zp[base + 1024];
        zg += zp[base + 2048];
        zo += zp[base + 3072];
    }
    float si = 1.f / (1.f + __expf(-zi));
    float sf = 1.f / (1.f + __expf(-zf));
    float so = 1.f / (1.f + __expf(-zo));
    float cn = sf * c_in[i] + si * tanhf(zg);
    float hn = so * tanhf(cn);
    c_new[i] = cn;
    h_new[i] = hn;
}

// ---- Kernel L: logits via bf16 MFMA. 500 blocks (N-tile 64) x 512 threads ----
__global__ __launch_bounds__(512) void k_logits_mfma(
        const float* __restrict__ h, const float* __restrict__ Wd,
        const float* __restrict__ bd, float* __restrict__ out) {
    __shared__ __align__(16) short blds[2 * 4 * 64 * 8];    // 8 KB
    const int tid  = threadIdx.x;
    const int wid  = tid >> 6;
    const int lane = tid & 63;
    const int g    = lane >> 4;
    const int r    = lane & 15;
    const int n0   = blockIdx.x << 6;     // N-tile base (64)

    f32x4 acc[4] = {};
    const float* hrow = h + ((size_t)((wid << 4) + r) << 10);

    for (int kt = 0; kt < Dc; kt += 64) {
        // stage W[kt..kt+63][n0..n0+63] as bf16 pairs, 1 task/thread
        {
            int pr = tid >> 4;            // 0..31
            int c  = tid & 15;
            const float* w0 = Wd + (size_t)(kt + (pr << 1)) * Vc + n0 + (c << 2);
            float4 wa = *(const float4*)w0;
            float4 wb = *(const float4*)(w0 + Vc);
            int ks = pr >> 4;
            int kk = (pr << 1) & 31;
            int gg = kk >> 3;
            int jj = kk & 7;
            float a0[4] = {wa.x, wa.y, wa.z, wa.w};
            float b0[4] = {wb.x, wb.y, wb.z, wb.w};
            #pragma unroll
            for (int i = 0; i < 4; ++i) {
                int n = (c << 2) + i;
                int nt = n >> 4;          // 0..3
                int inner = (gg << 4) | (n & 15);
                int Xs = ((((ks << 2) + nt) << 6) | inner) ^ nt;
                *(unsigned*)&blds[(Xs << 3) + jj] = pack2(a0[i], b0[i]);
            }
        }
        __syncthreads();

        #pragma unroll
        for (int ks = 0; ks < 2; ++ks) {
            const float* hp = hrow + kt + (ks << 5) + (g << 3);
            float4 h0 = *(const float4*)hp;
            float4 h1 = *(const float4*)(hp + 4);
            bf16x8 af;
            af[0] = f2bf(h0.x); af[1] = f2bf(h0.y); af[2] = f2bf(h0.z); af[3] = f2bf(h0.w);
            af[4] = f2bf(h1.x); af[5] = f2bf(h1.y); af[6] = f2bf(h1.z); af[7] = f2bf(h1.w);
            #pragma unroll
            for (int nt = 0; nt < 4; ++nt) {
                int Xs = ((((ks << 2) + nt) << 6) | lane) ^ nt;
                bf16x8 bfr = *(const bf16x8*)&blds[Xs << 3];
                acc[nt] = __builtin_amdgcn_mfma_f32_16x16x32_bf16(af, bfr, acc[nt], 0, 0, 0);
            }
        }
        __syncthreads();
    }

    #pragma unroll
    for (int nt = 0; nt < 4; ++nt) {
        int col = n0 + (nt << 4) + r;
        float bias = bd[col];
        #pragma unroll
        for (int j = 0; j < 4; ++j) {
            int row = (wid << 4) + (g << 2) + j;
            out[(size_t)row * Vc + col] = acc[nt][j] + bias;
        }
    }
}

extern "C" void kernel_launch(void* const* d_in, const int* in_sizes, int n_in,
                              void* d_out, int out_size, void* d_ws, size_t ws_size,
                              hipStream_t stream) {
    const int*   idx = (const int*)d_in[0];
    const float* enc = (const float*)d_in[1];
    const float* h   = (const float*)d_in[2];
    const float* c   = (const float*)d_in[3];
    const float* emb = (const float*)d_in[4];
    const float* Wl  = (const float*)d_in[5];
    const float* Ul  = (const float*)d_in[6];
    const float* bl  = (const float*)d_in[7];
    const float* Wd  = (const float*)d_in[8];
    const float* bd  = (const float*)d_in[9];

    float* out    = (float*)d_out;
    float* logits = out;                 // 4,096,000
    float* h_new  = out + 4096000;
    float* c_new  = out + 4227072;
    float* attn   = out + 4358144;
    float* ctx    = out + 4390912;

    // Scratch inside the logits region (k_logits_mfma overwrites all of it last).
    // Timeline: ctx_part & scores (att1) -> consumed by att2 -> z_part (zgemm,
    // overwrites both) -> consumed by gates -> logits.
    float* ctx_part = out;               // 4*128*1024 = 524,288
    float* scores_g = out + 524288;      // 32,768
    float* z_part   = out;               // 7 * 524,288 = 3,670,016
    float* x_buf    = out + 3670016;     // 128*2368 = 303,104 (ends 3,973,120)

    hipLaunchKernelGGL(k_att1, dim3(4, 128), dim3(256), 0, stream, enc, h, scores_g, ctx_part);
    hipLaunchKernelGGL(k_att2, dim3(128), dim3(256), 0, stream, ctx_part, scores_g, idx, emb, h,
                       ctx, attn, x_buf);
    hipLaunchKernelGGL(k_zgemm_mfma, dim3(32, KSPLIT), dim3(512), 0, stream, x_buf, Wl, Ul, z_part);
    hipLaunchKernelGGL(k_gates, dim3(512), dim3(256), 0, stream, z_part, bl, c, h_new, c_new);
    hipLaunchKernelGGL(k_logits_mfma, dim3(500), dim3(512), 0, stream, h_new, Wd, bd, logits);
}

// Round 6
// 104.735 us; speedup vs baseline: 2.8765x; 1.2102x over previous
//
#include <hip/hip_runtime.h>
#include <hip/hip_bf16.h>
#include <cmath>

// B=128, T=256, D=1024, V=32000, E=300
// d_out (floats): logits[0..4096000), h_new[4096000), c_new[4227072),
//                 attn[4358144), context[4390912), total 4521984

#define Bc 128
#define Tc 256
#define Dc 1024
#define Vc 32000
#define Ec 300
#define KREAL 2348        // D + E + D
#define KXP 2688          // padded: 7 splits x 6 steps x 64
#define KSPLIT 7
#define N4 4096

typedef __attribute__((ext_vector_type(8))) short bf16x8;
typedef __attribute__((ext_vector_type(4))) float f32x4;

static __device__ __forceinline__ short f2bf(float x) {
    __hip_bfloat16 b = __float2bfloat16(x);   // RNE
    return *reinterpret_cast<short*>(&b);
}
static __device__ __forceinline__ unsigned pack2(float a, float b) {
    return (unsigned)(unsigned short)f2bf(a) | ((unsigned)(unsigned short)f2bf(b) << 16);
}

// ---- A1: per (tc,b): scores for 32 t's, partial context. grid (8,128) x 256 ----
__global__ void k_att1(const float* __restrict__ enc, const float* __restrict__ h,
                       float* __restrict__ scores_g, float* __restrict__ ctx_part) {
    const int tc = blockIdx.x;            // 0..7
    const int b  = blockIdx.y;
    const int tid = threadIdx.x;
    const int wave = tid >> 6, lane = tid & 63;
    __shared__ float s_lds[32];

    const float4* h4 = (const float4*)(h + ((size_t)b << 10));
    float4 hv0 = h4[lane], hv1 = h4[lane + 64], hv2 = h4[lane + 128], hv3 = h4[lane + 192];

    #pragma unroll 2
    for (int i = 0; i < 8; ++i) {
        int tl = (wave << 3) + i;
        int t  = (tc << 5) + tl;
        const float4* e4 = (const float4*)(enc + ((size_t)(b * Tc + t) << 10));
        float4 e0 = e4[lane], e1 = e4[lane + 64], e2 = e4[lane + 128], e3 = e4[lane + 192];
        float d = e0.x*hv0.x + e0.y*hv0.y + e0.z*hv0.z + e0.w*hv0.w
                + e1.x*hv1.x + e1.y*hv1.y + e1.z*hv1.z + e1.w*hv1.w
                + e2.x*hv2.x + e2.y*hv2.y + e2.z*hv2.z + e2.w*hv2.w
                + e3.x*hv3.x + e3.y*hv3.y + e3.z*hv3.z + e3.w*hv3.w;
        #pragma unroll
        for (int off = 32; off; off >>= 1) d += __shfl_xor(d, off, 64);
        if (lane == 0) { s_lds[tl] = d; scores_g[(b << 8) + t] = d; }
    }
    __syncthreads();

    const float* ep = enc + ((size_t)(b * Tc + (tc << 5)) << 10) + (tid << 2);
    float4 acc = {0.f, 0.f, 0.f, 0.f};
    #pragma unroll 8
    for (int tl = 0; tl < 32; ++tl) {
        float4 v = *(const float4*)(ep + ((size_t)tl << 10));
        float s = s_lds[tl];
        acc.x += s * v.x; acc.y += s * v.y; acc.z += s * v.z; acc.w += s * v.w;
    }
    *(float4*)(ctx_part + (((size_t)(tc << 7) + b) << 10) + (tid << 2)) = acc;
}

// ---- A2: reduce ctx; softmax->attn; pack x_bf16 = [ctx, emb, h, 0]. 128 x 256 ----
__global__ void k_att2(const float* __restrict__ ctx_part, const float* __restrict__ scores_g,
                       const int* __restrict__ idx, const float* __restrict__ emb_table,
                       const float* __restrict__ h,
                       float* __restrict__ ctx_out, float* __restrict__ attn_out,
                       unsigned short* __restrict__ x_bf) {
    const int b = blockIdx.x;
    const int tid = threadIdx.x;
    __shared__ float red[256];

    float4 cv = {0.f, 0.f, 0.f, 0.f};
    #pragma unroll
    for (int tc = 0; tc < 8; ++tc) {
        float4 s = *(const float4*)(ctx_part + (((size_t)(tc << 7) + b) << 10) + (tid << 2));
        cv.x += s.x; cv.y += s.y; cv.z += s.z; cv.w += s.w;
    }
    *(float4*)(ctx_out + ((size_t)b << 10) + (tid << 2)) = cv;

    unsigned short* xb = x_bf + (size_t)b * KXP;
    uint2 p0; p0.x = pack2(cv.x, cv.y); p0.y = pack2(cv.z, cv.w);
    *(uint2*)&xb[tid << 2] = p0;

    int row = idx[b];
    for (int i = tid; i < Ec; i += 256)
        xb[Dc + i] = (unsigned short)f2bf(emb_table[(size_t)row * Ec + i]);

    float4 hv = *(const float4*)(h + ((size_t)b << 10) + (tid << 2));
    uint2 p1; p1.x = pack2(hv.x, hv.y); p1.y = pack2(hv.z, hv.w);
    *(uint2*)&xb[(Dc + Ec) + (tid << 2)] = p1;

    for (int i = tid; i < KXP - KREAL; i += 256) xb[KREAL + i] = 0;

    float v = scores_g[(b << 8) + tid];
    red[tid] = v;
    __syncthreads();
    for (int s = 128; s; s >>= 1) { if (tid < s) red[tid] = fmaxf(red[tid], red[tid + s]); __syncthreads(); }
    float m = red[0];
    __syncthreads();
    float e = __expf(v - m);
    red[tid] = e;
    __syncthreads();
    for (int s = 128; s; s >>= 1) { if (tid < s) red[tid] += red[tid + s]; __syncthreads(); }
    attn_out[(b << 8) + tid] = e / red[0];
}

// ---- Z: z partials, bf16 MFMA, LDS dbuf + early-issue. grid (64,7) x 512 ----
__global__ __launch_bounds__(512) void k_zgemm_mfma(
        const unsigned short* __restrict__ xbf, const float* __restrict__ Wl,
        const float* __restrict__ Ul, float* __restrict__ z_part) {
    __shared__ __align__(16) short blds[2 * 8 * 64 * 8];   // 16 KB
    const int tid  = threadIdx.x;
    const int wid  = tid >> 6;
    const int lane = tid & 63;
    const int g    = lane >> 4;
    const int r    = lane & 15;
    const int n0   = blockIdx.x << 6;     // 64-wide n tile
    const int ksp  = blockIdx.y;          // 0..6, steps ksp*6 .. ksp*6+5

    const int pr = tid >> 4;
    const int c  = tid & 15;
    const int kk = (pr << 1) & 31;
    const int gg = kk >> 3, jj = kk & 7;
    const int ks0 = pr >> 4;              // 0 or 1

    f32x4 acc[4] = {};
    const unsigned short* xrow = xbf + (size_t)((wid << 4) + r) * KXP;

    float4 wra[2], wrb[2];
    bf16x8 areg[2][2];

    auto loadWU = [&](int gk) -> float4 {
        if (gk < 1324) return *(const float4*)(Wl + (size_t)gk * N4 + n0 + (c << 2));
        if (gk < KREAL) return *(const float4*)(Ul + (size_t)(gk - 1324) * N4 + n0 + (c << 2));
        return float4{0.f, 0.f, 0.f, 0.f};
    };

    // prologue: tile 0
    {
        const int kt = (ksp * 6) << 6;
        wra[0] = loadWU(kt + (pr << 1));
        wrb[0] = loadWU(kt + (pr << 1) + 1);
        areg[0][0] = *(const bf16x8*)&xrow[kt + (g << 3)];
        areg[0][1] = *(const bf16x8*)&xrow[kt + 32 + (g << 3)];
    }

    #pragma unroll
    for (int t = 0; t < 6; ++t) {
        const int cur = t & 1;
        const int coff = cur << 12;       // shorts
        {
            const float av[4] = {wra[cur].x, wra[cur].y, wra[cur].z, wra[cur].w};
            const float bv[4] = {wrb[cur].x, wrb[cur].y, wrb[cur].z, wrb[cur].w};
            #pragma unroll
            for (int i = 0; i < 4; ++i) {
                int n = (c << 2) + i;
                int nt = n >> 4;
                int inner = (gg << 4) | (n & 15);
                int Xs = ((((ks0 << 2) + nt) << 6) | inner) ^ nt;
                *(unsigned*)&blds[coff + (Xs << 3) + jj] = pack2(av[i], bv[i]);
            }
        }
        if (t < 5) {
            const int kt = ((ksp * 6) + t + 1) << 6;
            wra[cur ^ 1] = loadWU(kt + (pr << 1));
            wrb[cur ^ 1] = loadWU(kt + (pr << 1) + 1);
            areg[cur ^ 1][0] = *(const bf16x8*)&xrow[kt + (g << 3)];
            areg[cur ^ 1][1] = *(const bf16x8*)&xrow[kt + 32 + (g << 3)];
        }
        __syncthreads();
        #pragma unroll
        for (int ks = 0; ks < 2; ++ks) {
            #pragma unroll
            for (int nt = 0; nt < 4; ++nt) {
                int Xs = ((((ks << 2) + nt) << 6) | lane) ^ nt;
                bf16x8 bfr = *(const bf16x8*)&blds[coff + (Xs << 3)];
                acc[nt] = __builtin_amdgcn_mfma_f32_16x16x32_bf16(areg[cur][ks], bfr, acc[nt], 0, 0, 0);
            }
        }
    }

    float* zp = z_part + ((size_t)ksp << 19);
    #pragma unroll
    for (int nt = 0; nt < 4; ++nt) {
        int col = n0 + (nt << 4) + r;
        #pragma unroll
        for (int j = 0; j < 4; ++j) {
            int rowm = (wid << 4) + (g << 2) + j;
            zp[((size_t)rowm << 12) + col] = acc[nt][j];
        }
    }
}

// ---- G: sum 7 partials + bias -> gates -> c_new, h_new, h_bf16 ----
__global__ void k_gates(const float* __restrict__ z_part, const float* __restrict__ b_lstm,
                        const float* __restrict__ c_in, float* __restrict__ h_new,
                        float* __restrict__ c_new, unsigned short* __restrict__ h_bf) {
    int i = blockIdx.x * 256 + threadIdx.x;    // < 131072
    int b = i >> 10, d = i & 1023;
    size_t base = ((size_t)b << 12) + d;
    float zi = b_lstm[d], zf = b_lstm[d + 1024], zg = b_lstm[d + 2048], zo = b_lstm[d + 3072];
    #pragma unroll
    for (int ks = 0; ks < KSPLIT; ++ks) {
        const float* zp = z_part + ((size_t)ks << 19);
        zi += zp[base];
        zf += zp[base + 1024];
        zg += zp[base + 2048];
        zo += zp[base + 3072];
    }
    float si = 1.f / (1.f + __expf(-zi));
    float sf = 1.f / (1.f + __expf(-zf));
    float so = 1.f / (1.f + __expf(-zo));
    float cn = sf * c_in[i] + si * tanhf(zg);
    float hn = so * tanhf(cn);
    c_new[i] = cn;
    h_new[i] = hn;
    h_bf[i] = (unsigned short)f2bf(hn);
}

// ---- L: logits, bf16 MFMA, K-step 128, LDS dbuf + early-issue. 500 x 512 ----
__global__ __launch_bounds__(512) void k_logits_mfma(
        const unsigned short* __restrict__ hbf, const float* __restrict__ Wd,
        const float* __restrict__ bd, float* __restrict__ out) {
    __shared__ __align__(16) short blds[2 * 16 * 64 * 8];   // 32 KB
    const int tid  = threadIdx.x;
    const int wid  = tid >> 6;
    const int lane = tid & 63;
    const int g    = lane >> 4;
    const int r    = lane & 15;
    const int n0   = blockIdx.x << 6;     // 64-wide n tile

    const int pr = tid >> 4;              // 0..31
    const int c  = tid & 15;
    const int kk = (pr << 1) & 31;
    const int gg = kk >> 3, jj = kk & 7;
    const int ksA = pr >> 4;              // task0: 0..1
    const int ksB = ksA + 2;              // task1: 2..3

    f32x4 acc[4] = {};
    const unsigned short* hrow = hbf + ((size_t)((wid << 4) + r) << 10);
    const float* wbase = Wd + (size_t)(pr << 1) * Vc + n0 + (c << 2);

    float4 wra[2], wrb[2], wrc[2], wrd[2];
    bf16x8 areg[2][4];

    // prologue: tile 0
    {
        wra[0] = *(const float4*)(wbase);
        wrb[0] = *(const float4*)(wbase + Vc);
        wrc[0] = *(const float4*)(wbase + (size_t)64 * Vc);
        wrd[0] = *(const float4*)(wbase + (size_t)65 * Vc);
        #pragma unroll
        for (int ks = 0; ks < 4; ++ks)
            areg[0][ks] = *(const bf16x8*)&hrow[(ks << 5) + (g << 3)];
    }

    #pragma unroll
    for (int t = 0; t < 8; ++t) {
        const int cur = t & 1;
        const int coff = cur << 13;       // shorts
        {
            const float a0[4] = {wra[cur].x, wra[cur].y, wra[cur].z, wra[cur].w};
            const float b0[4] = {wrb[cur].x, wrb[cur].y, wrb[cur].z, wrb[cur].w};
            const float c0[4] = {wrc[cur].x, wrc[cur].y, wrc[cur].z, wrc[cur].w};
            const float d0[4] = {wrd[cur].x, wrd[cur].y, wrd[cur].z, wrd[cur].w};
            #pragma unroll
            for (int i = 0; i < 4; ++i) {
                int n = (c << 2) + i;
                int nt = n >> 4;
                int inner = (gg << 4) | (n & 15);
                int XsA = ((((ksA << 2) + nt) << 6) | inner) ^ nt;
                int XsB = ((((ksB << 2) + nt) << 6) | inner) ^ nt;
                *(unsigned*)&blds[coff + (XsA << 3) + jj] = pack2(a0[i], b0[i]);
                *(unsigned*)&blds[coff + (XsB << 3) + jj] = pack2(c0[i], d0[i]);
            }
        }
        if (t < 7) {
            const float* wb2 = wbase + (size_t)((t + 1) << 7) * Vc;
            wra[cur ^ 1] = *(const float4*)(wb2);
            wrb[cur ^ 1] = *(const float4*)(wb2 + Vc);
            wrc[cur ^ 1] = *(const float4*)(wb2 + (size_t)64 * Vc);
            wrd[cur ^ 1] = *(const float4*)(wb2 + (size_t)65 * Vc);
            #pragma unroll
            for (int ks = 0; ks < 4; ++ks)
                areg[cur ^ 1][ks] = *(const bf16x8*)&hrow[((t + 1) << 7) + (ks << 5) + (g << 3)];
        }
        __syncthreads();
        #pragma unroll
        for (int ks = 0; ks < 4; ++ks) {
            #pragma unroll
            for (int nt = 0; nt < 4; ++nt) {
                int Xs = ((((ks << 2) + nt) << 6) | lane) ^ nt;
                bf16x8 bfr = *(const bf16x8*)&blds[coff + (Xs << 3)];
                acc[nt] = __builtin_amdgcn_mfma_f32_16x16x32_bf16(areg[cur][ks], bfr, acc[nt], 0, 0, 0);
            }
        }
    }

    #pragma unroll
    for (int nt = 0; nt < 4; ++nt) {
        int col = n0 + (nt << 4) + r;
        float bias = bd[col];
        #pragma unroll
        for (int j = 0; j < 4; ++j) {
            int row = (wid << 4) + (g << 2) + j;
            out[(size_t)row * Vc + col] = acc[nt][j] + bias;
        }
    }
}

extern "C" void kernel_launch(void* const* d_in, const int* in_sizes, int n_in,
                              void* d_out, int out_size, void* d_ws, size_t ws_size,
                              hipStream_t stream) {
    const int*   idx = (const int*)d_in[0];
    const float* enc = (const float*)d_in[1];
    const float* h   = (const float*)d_in[2];
    const float* c   = (const float*)d_in[3];
    const float* emb = (const float*)d_in[4];
    const float* Wl  = (const float*)d_in[5];
    const float* Ul  = (const float*)d_in[6];
    const float* bl  = (const float*)d_in[7];
    const float* Wd  = (const float*)d_in[8];
    const float* bd  = (const float*)d_in[9];

    float* out    = (float*)d_out;
    float* logits = out;                 // 4,096,000
    float* h_new  = out + 4096000;
    float* c_new  = out + 4227072;
    float* attn   = out + 4358144;
    float* ctx    = out + 4390912;

    // Scratch that is consumed BEFORE k_logits_mfma may live in the logits
    // region; anything k_logits_mfma READS must NOT (it writes [0,4096000)).
    // ctx_part+scores (att1->att2) and z_part (zgemm->gates) are consumed
    // earlier -> logits region. x_bf16 (att2->zgemm) and h_bf16
    // (gates->logits) go to d_ws (~0.95 MB) to avoid the R5 read/write race.
    float*          ctx_part = out;                  // 8*131072 = 1,048,576
    float*          scores_g = out + 1048576;        // 32,768 (ends 1,081,344)
    float*          z_part   = out;                  // 7*524,288 = 3,670,016
    unsigned short* x_bf16   = (unsigned short*)d_ws;            // 344,064 shorts
    unsigned short* h_bf16   = (unsigned short*)d_ws + 344064;   // 131,072 shorts (total 950,272 B)

    hipLaunchKernelGGL(k_att1, dim3(8, 128), dim3(256), 0, stream, enc, h, scores_g, ctx_part);
    hipLaunchKernelGGL(k_att2, dim3(128), dim3(256), 0, stream, ctx_part, scores_g, idx, emb, h,
                       ctx, attn, x_bf16);
    hipLaunchKernelGGL(k_zgemm_mfma, dim3(64, KSPLIT), dim3(512), 0, stream, x_bf16, Wl, Ul, z_part);
    hipLaunchKernelGGL(k_gates, dim3(512), dim3(256), 0, stream, z_part, bl, c, h_new, c_new, h_bf16);
    hipLaunchKernelGGL(k_logits_mfma, dim3(500), dim3(512), 0, stream, h_bf16, Wd, bd, logits);
}

// Round 7
// 90.905 us; speedup vs baseline: 3.3141x; 1.1521x over previous
//
#include <hip/hip_runtime.h>
#include <hip/hip_bf16.h>
#include <cmath>

// B=128, T=256, D=1024, V=32000, E=300
// d_out (floats): logits[0..4096000), h_new[4096000), c_new[4227072),
//                 attn[4358144), context[4390912), total 4521984

#define Bc 128
#define Tc 256
#define Dc 1024
#define Vc 32000
#define Ec 300
#define KREAL 2348        // D + E + D
#define KXP 2688          // padded: 7 splits x 6 steps x 64
#define KSPLIT 7
#define N4 4096

typedef __attribute__((ext_vector_type(8))) short bf16x8;
typedef __attribute__((ext_vector_type(4))) float f32x4;

static __device__ __forceinline__ short f2bf(float x) {
    __hip_bfloat16 b = __float2bfloat16(x);   // RNE
    return *reinterpret_cast<short*>(&b);
}
static __device__ __forceinline__ unsigned pack2(float a, float b) {
    return (unsigned)(unsigned short)f2bf(a) | ((unsigned)(unsigned short)f2bf(b) << 16);
}

// ---- A1 (single-pass): per (tc,b): scores + context partial for 64 t's.
//      grid (4,128) x 256. enc read EXACTLY ONCE (score & ctx from registers).
__global__ void k_att1(const float* __restrict__ enc, const float* __restrict__ h,
                       float* __restrict__ scores_g, float* __restrict__ ctx_part) {
    const int tc = blockIdx.x;            // 0..3 (64-row chunk)
    const int b  = blockIdx.y;
    const int tid = threadIdx.x;
    const int wave = tid >> 6, lane = tid & 63;
    __shared__ float s_acc[4][1024];      // 16 KB

    const float4* h4 = (const float4*)(h + ((size_t)b << 10));
    float4 hv0 = h4[lane], hv1 = h4[lane + 64], hv2 = h4[lane + 128], hv3 = h4[lane + 192];

    float4 a0 = {0,0,0,0}, a1 = {0,0,0,0}, a2 = {0,0,0,0}, a3 = {0,0,0,0};
    const int t0 = (tc << 6) + (wave << 4);            // this wave's first row
    const float4* e4 = (const float4*)(enc + ((size_t)(b * Tc + t0) << 10));

    #pragma unroll 2
    for (int i = 0; i < 16; ++i) {
        float4 e0 = e4[lane], e1 = e4[lane + 64], e2 = e4[lane + 128], e3 = e4[lane + 192];
        e4 += 256;                                      // next row
        float d = e0.x*hv0.x + e0.y*hv0.y + e0.z*hv0.z + e0.w*hv0.w
                + e1.x*hv1.x + e1.y*hv1.y + e1.z*hv1.z + e1.w*hv1.w
                + e2.x*hv2.x + e2.y*hv2.y + e2.z*hv2.z + e2.w*hv2.w
                + e3.x*hv3.x + e3.y*hv3.y + e3.z*hv3.z + e3.w*hv3.w;
        #pragma unroll
        for (int off = 32; off; off >>= 1) d += __shfl_xor(d, off, 64);   // all lanes get d
        if (lane == 0) scores_g[(b << 8) + t0 + i] = d;
        a0.x += d*e0.x; a0.y += d*e0.y; a0.z += d*e0.z; a0.w += d*e0.w;
        a1.x += d*e1.x; a1.y += d*e1.y; a1.z += d*e1.z; a1.w += d*e1.w;
        a2.x += d*e2.x; a2.y += d*e2.y; a2.z += d*e2.z; a2.w += d*e2.w;
        a3.x += d*e3.x; a3.y += d*e3.y; a3.z += d*e3.z; a3.w += d*e3.w;
    }

    // cross-wave column sum: lane covers cols {4l, 256+4l, 512+4l, 768+4l}+0..3
    *(float4*)&s_acc[wave][lane << 2]         = a0;
    *(float4*)&s_acc[wave][256 + (lane << 2)] = a1;
    *(float4*)&s_acc[wave][512 + (lane << 2)] = a2;
    *(float4*)&s_acc[wave][768 + (lane << 2)] = a3;
    __syncthreads();
    float4 r0 = *(const float4*)&s_acc[0][tid << 2];
    float4 r1 = *(const float4*)&s_acc[1][tid << 2];
    float4 r2 = *(const float4*)&s_acc[2][tid << 2];
    float4 r3 = *(const float4*)&s_acc[3][tid << 2];
    float4 r;
    r.x = r0.x + r1.x + r2.x + r3.x;
    r.y = r0.y + r1.y + r2.y + r3.y;
    r.z = r0.z + r1.z + r2.z + r3.z;
    r.w = r0.w + r1.w + r2.w + r3.w;
    *(float4*)(ctx_part + (((size_t)(tc << 7) + b) << 10) + (tid << 2)) = r;
}

// ---- A2: reduce 4 ctx parts; softmax->attn; pack x_bf16 = [ctx, emb, h, 0] ----
__global__ void k_att2(const float* __restrict__ ctx_part, const float* __restrict__ scores_g,
                       const int* __restrict__ idx, const float* __restrict__ emb_table,
                       const float* __restrict__ h,
                       float* __restrict__ ctx_out, float* __restrict__ attn_out,
                       unsigned short* __restrict__ x_bf) {
    const int b = blockIdx.x;
    const int tid = threadIdx.x;
    __shared__ float red[256];

    float4 cv = {0.f, 0.f, 0.f, 0.f};
    #pragma unroll
    for (int tc = 0; tc < 4; ++tc) {
        float4 s = *(const float4*)(ctx_part + (((size_t)(tc << 7) + b) << 10) + (tid << 2));
        cv.x += s.x; cv.y += s.y; cv.z += s.z; cv.w += s.w;
    }
    *(float4*)(ctx_out + ((size_t)b << 10) + (tid << 2)) = cv;

    unsigned short* xb = x_bf + (size_t)b * KXP;
    uint2 p0; p0.x = pack2(cv.x, cv.y); p0.y = pack2(cv.z, cv.w);
    *(uint2*)&xb[tid << 2] = p0;

    int row = idx[b];
    for (int i = tid; i < Ec; i += 256)
        xb[Dc + i] = (unsigned short)f2bf(emb_table[(size_t)row * Ec + i]);

    float4 hv = *(const float4*)(h + ((size_t)b << 10) + (tid << 2));
    uint2 p1; p1.x = pack2(hv.x, hv.y); p1.y = pack2(hv.z, hv.w);
    *(uint2*)&xb[(Dc + Ec) + (tid << 2)] = p1;

    for (int i = tid; i < KXP - KREAL; i += 256) xb[KREAL + i] = 0;

    float v = scores_g[(b << 8) + tid];
    red[tid] = v;
    __syncthreads();
    for (int s = 128; s; s >>= 1) { if (tid < s) red[tid] = fmaxf(red[tid], red[tid + s]); __syncthreads(); }
    float m = red[0];
    __syncthreads();
    float e = __expf(v - m);
    red[tid] = e;
    __syncthreads();
    for (int s = 128; s; s >>= 1) { if (tid < s) red[tid] += red[tid + s]; __syncthreads(); }
    attn_out[(b << 8) + tid] = e / red[0];
}

// ---- Z: z partials, bf16 MFMA, LDS dbuf + early-issue. grid (64,7) x 512 ----
__global__ __launch_bounds__(512) void k_zgemm_mfma(
        const unsigned short* __restrict__ xbf, const float* __restrict__ Wl,
        const float* __restrict__ Ul, float* __restrict__ z_part) {
    __shared__ __align__(16) short blds[2 * 8 * 64 * 8];   // 16 KB
    const int tid  = threadIdx.x;
    const int wid  = tid >> 6;
    const int lane = tid & 63;
    const int g    = lane >> 4;
    const int r    = lane & 15;
    const int n0   = blockIdx.x << 6;     // 64-wide n tile
    const int ksp  = blockIdx.y;          // 0..6, steps ksp*6 .. ksp*6+5

    const int pr = tid >> 4;
    const int c  = tid & 15;
    const int kk = (pr << 1) & 31;
    const int gg = kk >> 3, jj = kk & 7;
    const int ks0 = pr >> 4;              // 0 or 1

    f32x4 acc[4] = {};
    const unsigned short* xrow = xbf + (size_t)((wid << 4) + r) * KXP;

    float4 wra[2], wrb[2];
    bf16x8 areg[2][2];

    auto loadWU = [&](int gk) -> float4 {
        if (gk < 1324) return *(const float4*)(Wl + (size_t)gk * N4 + n0 + (c << 2));
        if (gk < KREAL) return *(const float4*)(Ul + (size_t)(gk - 1324) * N4 + n0 + (c << 2));
        return float4{0.f, 0.f, 0.f, 0.f};
    };

    // prologue: tile 0
    {
        const int kt = (ksp * 6) << 6;
        wra[0] = loadWU(kt + (pr << 1));
        wrb[0] = loadWU(kt + (pr << 1) + 1);
        areg[0][0] = *(const bf16x8*)&xrow[kt + (g << 3)];
        areg[0][1] = *(const bf16x8*)&xrow[kt + 32 + (g << 3)];
    }

    #pragma unroll
    for (int t = 0; t < 6; ++t) {
        const int cur = t & 1;
        const int coff = cur << 12;       // shorts
        {
            const float av[4] = {wra[cur].x, wra[cur].y, wra[cur].z, wra[cur].w};
            const float bv[4] = {wrb[cur].x, wrb[cur].y, wrb[cur].z, wrb[cur].w};
            #pragma unroll
            for (int i = 0; i < 4; ++i) {
                int n = (c << 2) + i;
                int nt = n >> 4;
                int inner = (gg << 4) | (n & 15);
                int Xs = ((((ks0 << 2) + nt) << 6) | inner) ^ nt;
                *(unsigned*)&blds[coff + (Xs << 3) + jj] = pack2(av[i], bv[i]);
            }
        }
        if (t < 5) {
            const int kt = ((ksp * 6) + t + 1) << 6;
            wra[cur ^ 1] = loadWU(kt + (pr << 1));
            wrb[cur ^ 1] = loadWU(kt + (pr << 1) + 1);
            areg[cur ^ 1][0] = *(const bf16x8*)&xrow[kt + (g << 3)];
            areg[cur ^ 1][1] = *(const bf16x8*)&xrow[kt + 32 + (g << 3)];
        }
        __syncthreads();
        #pragma unroll
        for (int ks = 0; ks < 2; ++ks) {
            #pragma unroll
            for (int nt = 0; nt < 4; ++nt) {
                int Xs = ((((ks << 2) + nt) << 6) | lane) ^ nt;
                bf16x8 bfr = *(const bf16x8*)&blds[coff + (Xs << 3)];
                acc[nt] = __builtin_amdgcn_mfma_f32_16x16x32_bf16(areg[cur][ks], bfr, acc[nt], 0, 0, 0);
            }
        }
    }

    float* zp = z_part + ((size_t)ksp << 19);
    #pragma unroll
    for (int nt = 0; nt < 4; ++nt) {
        int col = n0 + (nt << 4) + r;
        #pragma unroll
        for (int j = 0; j < 4; ++j) {
            int rowm = (wid << 4) + (g << 2) + j;
            zp[((size_t)rowm << 12) + col] = acc[nt][j];
        }
    }
}

// ---- G: sum 7 partials + bias -> gates -> c_new, h_new, h_bf16 ----
__global__ void k_gates(const float* __restrict__ z_part, const float* __restrict__ b_lstm,
                        const float* __restrict__ c_in, float* __restrict__ h_new,
                        float* __restrict__ c_new, unsigned short* __restrict__ h_bf) {
    int i = blockIdx.x * 256 + threadIdx.x;    // < 131072
    int b = i >> 10, d = i & 1023;
    size_t base = ((size_t)b << 12) + d;
    float zi = b_lstm[d], zf = b_lstm[d + 1024], zg = b_lstm[d + 2048], zo = b_lstm[d + 3072];
    #pragma unroll
    for (int ks = 0; ks < KSPLIT; ++ks) {
        const float* zp = z_part + ((size_t)ks << 19);
        zi += zp[base];
        zf += zp[base + 1024];
        zg += zp[base + 2048];
        zo += zp[base + 3072];
    }
    float si = 1.f / (1.f + __expf(-zi));
    float sf = 1.f / (1.f + __expf(-zf));
    float so = 1.f / (1.f + __expf(-zo));
    float cn = sf * c_in[i] + si * tanhf(zg);
    float hn = so * tanhf(cn);
    c_new[i] = cn;
    h_new[i] = hn;
    h_bf[i] = (unsigned short)f2bf(hn);
}

// ---- L: logits, bf16 MFMA, K-step 128, LDS dbuf + early-issue. 500 x 512 ----
__global__ __launch_bounds__(512) void k_logits_mfma(
        const unsigned short* __restrict__ hbf, const float* __restrict__ Wd,
        const float* __restrict__ bd, float* __restrict__ out) {
    __shared__ __align__(16) short blds[2 * 16 * 64 * 8];   // 32 KB
    const int tid  = threadIdx.x;
    const int wid  = tid >> 6;
    const int lane = tid & 63;
    const int g    = lane >> 4;
    const int r    = lane & 15;
    const int n0   = blockIdx.x << 6;     // 64-wide n tile

    const int pr = tid >> 4;              // 0..31
    const int c  = tid & 15;
    const int kk = (pr << 1) & 31;
    const int gg = kk >> 3, jj = kk & 7;
    const int ksA = pr >> 4;              // task0: 0..1
    const int ksB = ksA + 2;              // task1: 2..3

    f32x4 acc[4] = {};
    const unsigned short* hrow = hbf + ((size_t)((wid << 4) + r) << 10);
    const float* wbase = Wd + (size_t)(pr << 1) * Vc + n0 + (c << 2);

    float4 wra[2], wrb[2], wrc[2], wrd[2];
    bf16x8 areg[2][4];

    // prologue: tile 0
    {
        wra[0] = *(const float4*)(wbase);
        wrb[0] = *(const float4*)(wbase + Vc);
        wrc[0] = *(const float4*)(wbase + (size_t)64 * Vc);
        wrd[0] = *(const float4*)(wbase + (size_t)65 * Vc);
        #pragma unroll
        for (int ks = 0; ks < 4; ++ks)
            areg[0][ks] = *(const bf16x8*)&hrow[(ks << 5) + (g << 3)];
    }

    #pragma unroll
    for (int t = 0; t < 8; ++t) {
        const int cur = t & 1;
        const int coff = cur << 13;       // shorts
        {
            const float a0[4] = {wra[cur].x, wra[cur].y, wra[cur].z, wra[cur].w};
            const float b0[4] = {wrb[cur].x, wrb[cur].y, wrb[cur].z, wrb[cur].w};
            const float c0[4] = {wrc[cur].x, wrc[cur].y, wrc[cur].z, wrc[cur].w};
            const float d0[4] = {wrd[cur].x, wrd[cur].y, wrd[cur].z, wrd[cur].w};
            #pragma unroll
            for (int i = 0; i < 4; ++i) {
                int n = (c << 2) + i;
                int nt = n >> 4;
                int inner = (gg << 4) | (n & 15);
                int XsA = ((((ksA << 2) + nt) << 6) | inner) ^ nt;
                int XsB = ((((ksB << 2) + nt) << 6) | inner) ^ nt;
                *(unsigned*)&blds[coff + (XsA << 3) + jj] = pack2(a0[i], b0[i]);
                *(unsigned*)&blds[coff + (XsB << 3) + jj] = pack2(c0[i], d0[i]);
            }
        }
        if (t < 7) {
            const float* wb2 = wbase + (size_t)((t + 1) << 7) * Vc;
            wra[cur ^ 1] = *(const float4*)(wb2);
            wrb[cur ^ 1] = *(const float4*)(wb2 + Vc);
            wrc[cur ^ 1] = *(const float4*)(wb2 + (size_t)64 * Vc);
            wrd[cur ^ 1] = *(const float4*)(wb2 + (size_t)65 * Vc);
            #pragma unroll
            for (int ks = 0; ks < 4; ++ks)
                areg[cur ^ 1][ks] = *(const bf16x8*)&hrow[((t + 1) << 7) + (ks << 5) + (g << 3)];
        }
        __syncthreads();
        #pragma unroll
        for (int ks = 0; ks < 4; ++ks) {
            #pragma unroll
            for (int nt = 0; nt < 4; ++nt) {
                int Xs = ((((ks << 2) + nt) << 6) | lane) ^ nt;
                bf16x8 bfr = *(const bf16x8*)&blds[coff + (Xs << 3)];
                acc[nt] = __builtin_amdgcn_mfma_f32_16x16x32_bf16(areg[cur][ks], bfr, acc[nt], 0, 0, 0);
            }
        }
    }

    #pragma unroll
    for (int nt = 0; nt < 4; ++nt) {
        int col = n0 + (nt << 4) + r;
        float bias = bd[col];
        #pragma unroll
        for (int j = 0; j < 4; ++j) {
            int row = (wid << 4) + (g << 2) + j;
            out[(size_t)row * Vc + col] = acc[nt][j] + bias;
        }
    }
}

extern "C" void kernel_launch(void* const* d_in, const int* in_sizes, int n_in,
                              void* d_out, int out_size, void* d_ws, size_t ws_size,
                              hipStream_t stream) {
    const int*   idx = (const int*)d_in[0];
    const float* enc = (const float*)d_in[1];
    const float* h   = (const float*)d_in[2];
    const float* c   = (const float*)d_in[3];
    const float* emb = (const float*)d_in[4];
    const float* Wl  = (const float*)d_in[5];
    const float* Ul  = (const float*)d_in[6];
    const float* bl  = (const float*)d_in[7];
    const float* Wd  = (const float*)d_in[8];
    const float* bd  = (const float*)d_in[9];

    float* out    = (float*)d_out;
    float* logits = out;                 // 4,096,000
    float* h_new  = out + 4096000;
    float* c_new  = out + 4227072;
    float* attn   = out + 4358144;
    float* ctx    = out + 4390912;

    // Scratch consumed BEFORE k_logits_mfma lives in the logits region;
    // anything k_logits_mfma READS lives in d_ws (it writes [0,4096000)).
    float*          ctx_part = out;                  // 4*131072 = 524,288
    float*          scores_g = out + 524288;         // 32,768 (ends 557,056)
    float*          z_part   = out;                  // 7*524,288 = 3,670,016
    unsigned short* x_bf16   = (unsigned short*)d_ws;            // 344,064 shorts
    unsigned short* h_bf16   = (unsigned short*)d_ws + 344064;   // 131,072 shorts (total 950,272 B)

    hipLaunchKernelGGL(k_att1, dim3(4, 128), dim3(256), 0, stream, enc, h, scores_g, ctx_part);
    hipLaunchKernelGGL(k_att2, dim3(128), dim3(256), 0, stream, ctx_part, scores_g, idx, emb, h,
                       ctx, attn, x_bf16);
    hipLaunchKernelGGL(k_zgemm_mfma, dim3(64, KSPLIT), dim3(512), 0, stream, x_bf16, Wl, Ul, z_part);
    hipLaunchKernelGGL(k_gates, dim3(512), dim3(256), 0, stream, z_part, bl, c, h_new, c_new, h_bf16);
    hipLaunchKernelGGL(k_logits_mfma, dim3(500), dim3(512), 0, stream, h_bf16, Wd, bd, logits);
}